// Round 10
// baseline (273.687 us; speedup 1.0000x reference)
//
#include <hip/hip_runtime.h>

// GraphAttentionLayer: x(8192,512) f32, support(8192,8192) i32{0,1},
// W(512,256) f32, a(512,1) f32  ->  out(8192,256) f32
//
// Decomposition (softmax shift cancels in numerator/denominator):
//   h = x@W (bf16 MFMA); s = h@a1, t = h@a2
//   top rows i<4096 : out = elu((eL*TL + eR*TR)/(eL*TL[256] + eR*TR[256]))
//   bot rows i>=4096: out = elu(TB/TB[256]),  TB = sup[4096:, :] @ (wb .* [h|1])
//
// v10: k_pack streams support once -> 8 MB bitmask (1 MB per XCD q-window,
// L2-resident). k_mgemm has NO LDS, NO barriers, NO manual waitcnt: each wave
// independently computes 32 rows x 136 cols x K=1024. A = int4 per 4 steps
// from bitmask (expand to bf16 frags in VALU); B = 9/8 dwordx4 frags per step
// straight from L2. acc<=72 VGPR, B transient 36, A 16 -> no spill at
// launch_bounds(128,3) (168 cap). 2048 blocks x 2 waves = 12 waves/CU TLP.
// Partials P[8][8192][272] plain stores; k_out combines.

typedef short bf16x8 __attribute__((ext_vector_type(8)));
typedef float f32x4 __attribute__((ext_vector_type(4)));

static __device__ __forceinline__ unsigned short f2bf(float f) {
    unsigned int u = __builtin_bit_cast(unsigned int, f);
    unsigned int r = (u + 0x7FFFu + ((u >> 16) & 1u)) >> 16;
    return (unsigned short)r;
}
static __device__ __forceinline__ float bf2f(unsigned short s) {
    unsigned int u = ((unsigned int)s) << 16;
    return __builtin_bit_cast(float, u);
}
// byte (8 bits of support) -> bf16x8 {0,1}
static __device__ __forceinline__ bf16x8 expand_byte(unsigned int b) {
    union { bf16x8 v; unsigned int u[4]; } r;
#pragma unroll
    for (int w = 0; w < 4; w++) {
        unsigned int lo = (b >> (2 * w)) & 1u;
        unsigned int hi = (b >> (2 * w + 1)) & 1u;
        r.u[w] = (lo ? 0x3F80u : 0u) | (hi ? 0x3F800000u : 0u);
    }
    return r.v;
}

// ---- k0: pack support -> bits[8192][1024] bytes; byte b bit i = sup[r][8b+i]
__global__ __launch_bounds__(256) void k_pack(const int* __restrict__ sup,
                                              unsigned char* __restrict__ bits) {
    int row = (blockIdx.x << 2) | (threadIdx.x >> 6);
    int ln = threadIdx.x & 63;
    const int* rp = sup + (long)row * 8192 + ln * 8;
    unsigned char* bp = bits + (long)row * 1024 + ln;
#pragma unroll 4
    for (int it = 0; it < 16; ++it) {
        int4 v0 = *(const int4*)(rp + it * 512);
        int4 v1 = *(const int4*)(rp + it * 512 + 4);
        unsigned int b = 0;
        b |= v0.x ? 1u : 0u;   b |= v0.y ? 2u : 0u;
        b |= v0.z ? 4u : 0u;   b |= v0.w ? 8u : 0u;
        b |= v1.x ? 16u : 0u;  b |= v1.y ? 32u : 0u;
        b |= v1.z ? 64u : 0u;  b |= v1.w ? 128u : 0u;
        bp[it * 64] = (unsigned char)b;
    }
}

// ---- k1a: x f32 -> bf16 row-major [8192][512]
__global__ __launch_bounds__(256) void k_cvt_x(const float* __restrict__ x,
                                               unsigned short* __restrict__ xb) {
    int i = (blockIdx.x * 256 + threadIdx.x) * 4;
    float4 v = *(const float4*)(x + i);
    ushort4 o = make_ushort4(f2bf(v.x), f2bf(v.y), f2bf(v.z), f2bf(v.w));
    *(ushort4*)(xb + i) = o;
}

// ---- k1b: W [512][256] f32 -> Wbt [256][512] bf16
__global__ __launch_bounds__(256) void k_cvt_w(const float* __restrict__ W,
                                               unsigned short* __restrict__ Wbt) {
    int idx = blockIdx.x * 256 + threadIdx.x;
    int n = idx >> 9, k = idx & 511;
    Wbt[idx] = f2bf(W[k * 256 + n]);
}

// ---- k2: h = xb @ Wbt^T. Writes h row-major bf16 AND B1t [272][8192] rows 0..255.
__global__ __launch_bounds__(256) void k_gemm_h(const unsigned short* __restrict__ xb,
                                                const unsigned short* __restrict__ Wbt,
                                                unsigned short* __restrict__ h,
                                                unsigned short* __restrict__ B1t) {
    __shared__ unsigned short Asm[128][72];
    __shared__ unsigned short Bsm[64][72];
    int tid = threadIdx.x;
    int wv = tid >> 6, ln = tid & 63;
    int m0 = blockIdx.x * 128, n0 = blockIdx.y * 64;

    f32x4 acc[2][4];
#pragma unroll
    for (int i = 0; i < 2; i++)
#pragma unroll
        for (int j = 0; j < 4; j++) acc[i][j] = (f32x4)0.0f;

    for (int k0 = 0; k0 < 512; k0 += 64) {
        {
            int r = tid >> 1, c = (tid & 1) * 32;
            const unsigned short* src = xb + (m0 + r) * 512 + k0 + c;
            *(bf16x8*)&Asm[r][c]      = *(const bf16x8*)(src);
            *(bf16x8*)&Asm[r][c + 8]  = *(const bf16x8*)(src + 8);
            *(bf16x8*)&Asm[r][c + 16] = *(const bf16x8*)(src + 16);
            *(bf16x8*)&Asm[r][c + 24] = *(const bf16x8*)(src + 24);
        }
        {
            int r = tid >> 2, c = (tid & 3) * 16;
            const unsigned short* src = Wbt + (n0 + r) * 512 + k0 + c;
            *(bf16x8*)&Bsm[r][c]     = *(const bf16x8*)(src);
            *(bf16x8*)&Bsm[r][c + 8] = *(const bf16x8*)(src + 8);
        }
        __syncthreads();
        int lr = ln & 15, lk = (ln >> 4) * 8;
#pragma unroll
        for (int ks = 0; ks < 2; ks++) {
            int kk = ks * 32 + lk;
            bf16x8 a0 = *(const bf16x8*)&Asm[wv * 32 + lr][kk];
            bf16x8 a1 = *(const bf16x8*)&Asm[wv * 32 + 16 + lr][kk];
#pragma unroll
            for (int nt = 0; nt < 4; nt++) {
                bf16x8 b = *(const bf16x8*)&Bsm[nt * 16 + lr][kk];
                acc[0][nt] = __builtin_amdgcn_mfma_f32_16x16x32_bf16(a0, b, acc[0][nt], 0, 0, 0);
                acc[1][nt] = __builtin_amdgcn_mfma_f32_16x16x32_bf16(a1, b, acc[1][nt], 0, 0, 0);
            }
        }
        __syncthreads();
    }
    int lr = ln & 15, lrow = (ln >> 4) * 4;
#pragma unroll
    for (int mt = 0; mt < 2; mt++) {
#pragma unroll
        for (int nt = 0; nt < 4; nt++) {
            int mg = m0 + wv * 32 + mt * 16 + lrow;
            int ng = n0 + nt * 16 + lr;
            ushort4 tb = make_ushort4(f2bf(acc[mt][nt][0]), f2bf(acc[mt][nt][1]),
                                      f2bf(acc[mt][nt][2]), f2bf(acc[mt][nt][3]));
            h[(mg + 0) * 256 + ng] = tb.x;
            h[(mg + 1) * 256 + ng] = tb.y;
            h[(mg + 2) * 256 + ng] = tb.z;
            h[(mg + 3) * 256 + ng] = tb.w;
            *(ushort4*)&B1t[ng * 8192 + mg] = tb;
        }
    }
}

// ---- k3: s[j], t[j]
__global__ __launch_bounds__(256) void k_st(const unsigned short* __restrict__ h,
                                            const float* __restrict__ a,
                                            float* __restrict__ s, float* __restrict__ t) {
    int wv = threadIdx.x >> 6, ln = threadIdx.x & 63;
    int j = blockIdx.x * 4 + wv;
    ushort4 hv = *(const ushort4*)(h + j * 256 + ln * 4);
    float4 a1 = *(const float4*)(a + ln * 4);
    float4 a2 = *(const float4*)(a + 256 + ln * 4);
    float s_ = bf2f(hv.x) * a1.x + bf2f(hv.y) * a1.y + bf2f(hv.z) * a1.z + bf2f(hv.w) * a1.w;
    float t_ = bf2f(hv.x) * a2.x + bf2f(hv.y) * a2.y + bf2f(hv.z) * a2.z + bf2f(hv.w) * a2.w;
#pragma unroll
    for (int off = 32; off; off >>= 1) {
        s_ += __shfl_down(s_, off);
        t_ += __shfl_down(t_, off);
    }
    if (ln == 0) { s[j] = s_; t[j] = t_; }
}

// ---- k3b: wb / eL / eR; fill B1t aux rows (256 = ones, 257..271 = 0)
__global__ __launch_bounds__(256) void k_weights(const float* __restrict__ s,
                                                 const float* __restrict__ t,
                                                 float* __restrict__ wb,
                                                 float* __restrict__ eL,
                                                 float* __restrict__ eR,
                                                 unsigned short* __restrict__ B1t) {
    int j = blockIdx.x * 256 + threadIdx.x;
    float eb = s[(2 * j) & 8191] + t[(2 * j + 1) & 8191];
    eb = eb > 0.0f ? eb : 0.2f * eb;
    wb[j] = expf(eb);
    if (j < 4096) {
        float cL = s[2 * j] + t[2 * j];
        cL = cL > 0.0f ? cL : 0.2f * cL;
        float cR = s[2 * j + 1] + t[2 * j + 1];
        cR = cR > 0.0f ? cR : 0.2f * cR;
        eL[j] = expf(cL);
        eR[j] = expf(cR);
    }
    B1t[256 * 8192 + j] = 0x3F80;
#pragma unroll
    for (int f = 257; f < 272; f++) B1t[f * 8192 + j] = 0;
}

// ---- k4: B2t[f][j] = wb[j] * B1t[f][j]
__global__ __launch_bounds__(256) void k_b2(const unsigned short* __restrict__ B1t,
                                            const float* __restrict__ wb,
                                            unsigned short* __restrict__ B2t) {
    int j = blockIdx.x * 256 + threadIdx.x;
    int f = blockIdx.y;
    B2t[f * 8192 + j] = f2bf(wb[j] * bf2f(B1t[f * 8192 + j]));
}

// ---- k5: masked GEMM v10 (no LDS / no barriers; see header).
template <int NF>
static __device__ __forceinline__ void mg_wave(const unsigned char* __restrict__ bits,
                                               long m0, int q,
                                               const unsigned short* __restrict__ bp,
                                               float* __restrict__ op, int ln) {
    const int4* ac0 = (const int4*)(bits + (m0 + (ln & 15)) * 1024 + q * 128);
    const int4* ac1 = (const int4*)(bits + (m0 + 16 + (ln & 15)) * 1024 + q * 128);
    int sh = (ln >> 4) * 8;

    f32x4 acc0[NF], acc1[NF];
#pragma unroll
    for (int f = 0; f < NF; f++) { acc0[f] = (f32x4)0.0f; acc1[f] = (f32x4)0.0f; }

#define MG_STEP(STEP, WX, WY) do {                                            \
        bf16x8 av0 = expand_byte(((unsigned int)(WX) >> sh) & 0xFFu);         \
        bf16x8 av1 = expand_byte(((unsigned int)(WY) >> sh) & 0xFFu);         \
        __builtin_amdgcn_s_setprio(1);                                        \
        _Pragma("unroll")                                                     \
        for (int f = 0; f < NF; f++) {                                        \
            bf16x8 bv = *(const bf16x8*)(bp + (long)f * 131072 + (STEP) * 32);\
            acc0[f] = __builtin_amdgcn_mfma_f32_16x16x32_bf16(av0, bv, acc0[f], 0, 0, 0); \
            acc1[f] = __builtin_amdgcn_mfma_f32_16x16x32_bf16(av1, bv, acc1[f], 0, 0, 0); \
        }                                                                     \
        __builtin_amdgcn_s_setprio(0);                                        \
    } while (0)

#pragma unroll 2
    for (int g = 0; g < 8; ++g) {
        int4 w0 = ac0[g];
        int4 w1 = ac1[g];
        MG_STEP(g * 4 + 0, w0.x, w1.x);
        MG_STEP(g * 4 + 1, w0.y, w1.y);
        MG_STEP(g * 4 + 2, w0.z, w1.z);
        MG_STEP(g * 4 + 3, w0.w, w1.w);
    }
#undef MG_STEP

    int lr = ln & 15, lrow = (ln >> 4) * 4;
#pragma unroll
    for (int f = 0; f < NF; f++) {
#pragma unroll
        for (int r = 0; r < 4; r++) {
            op[(long)(lrow + r) * 272 + f * 16 + lr]      = acc0[f][r];
            op[(long)(16 + lrow + r) * 272 + f * 16 + lr] = acc1[f][r];
        }
    }
}

__global__ __launch_bounds__(128, 3) void k_mgemm(const unsigned char* __restrict__ bits,
                                                  const unsigned short* __restrict__ B1t,
                                                  const unsigned short* __restrict__ B2t,
                                                  float* __restrict__ P) {
    int half = threadIdx.x >> 6, ln = threadIdx.x & 63;
    int b = blockIdx.x;
    int q = b & 7;               // XCD-pinned K-window (K0 = q*1024)
    int strip = b >> 3;          // 0..255 (32-row strip)
    long m0 = (long)strip * 32;
    const unsigned short* Bt = (strip < 128) ? B1t : B2t;
    int n0 = half * 144;         // half 0: frags 0..8 (cols 0..143); half 1: 9..16

    const unsigned short* bp = Bt + (long)(n0 + (ln & 15)) * 8192 + q * 1024 + (ln >> 4) * 8;
    float* op = P + ((long)q * 8192 + m0) * 272 + n0;

    if (half == 0) mg_wave<9>(bits, m0, q, bp, op, ln);
    else           mg_wave<8>(bits, m0, q, bp, op, ln);
}

// ---- k6: combine 8 partials + elu
__global__ __launch_bounds__(256) void k_out(const float* __restrict__ P,
                                             const float* __restrict__ eL,
                                             const float* __restrict__ eR,
                                             float* __restrict__ outp) {
    int i = blockIdx.x, f = threadIdx.x;
    const float* p = P + (long)i * 272;
    const long QS = 8192l * 272;
    float num, den;
    if (i < 4096) {
        float tln = 0, trn = 0, tld = 0, trd = 0;
#pragma unroll
        for (int q = 0; q < 4; q++) { tln += p[q * QS + f]; tld += p[q * QS + 256]; }
#pragma unroll
        for (int q = 4; q < 8; q++) { trn += p[q * QS + f]; trd += p[q * QS + 256]; }
        float el = eL[i], er = eR[i];
        num = el * tln + er * trn;
        den = el * tld + er * trd;
    } else {
        num = 0; den = 0;
#pragma unroll
        for (int q = 0; q < 8; q++) { num += p[q * QS + f]; den += p[q * QS + 256]; }
    }
    float r = num / den;
    outp[(long)i * 256 + f] = r > 0.0f ? r : expm1f(r);
}

extern "C" void kernel_launch(void* const* d_in, const int* in_sizes, int n_in,
                              void* d_out, int out_size, void* d_ws, size_t ws_size,
                              hipStream_t stream) {
    (void)in_sizes; (void)n_in; (void)out_size; (void)ws_size;
    const float* x = (const float*)d_in[0];
    const int* sup = (const int*)d_in[1];
    const float* W = (const float*)d_in[2];
    const float* a = (const float*)d_in[3];
    float* outp = (float*)d_out;

    char* ws = (char*)d_ws;
    size_t off = 0;
    auto alloc = [&](size_t bytes) -> void* {
        void* p = ws + off;
        off += (bytes + 255) & ~(size_t)255;
        return p;
    };
    unsigned short* xb  = (unsigned short*)alloc(8192 * 512 * 2);
    unsigned short* Wbt = (unsigned short*)alloc(256 * 512 * 2);
    unsigned short* h   = (unsigned short*)alloc(8192 * 256 * 2);
    unsigned short* B1t = (unsigned short*)alloc(272 * 8192 * 2);
    unsigned short* B2t = (unsigned short*)alloc(272 * 8192 * 2);
    unsigned char* bits = (unsigned char*)alloc((size_t)8192 * 1024);   // 8 MB
    float* s   = (float*)alloc(8192 * 4);
    float* t   = (float*)alloc(8192 * 4);
    float* wb  = (float*)alloc(8192 * 4);
    float* eL  = (float*)alloc(4096 * 4);
    float* eR  = (float*)alloc(4096 * 4);
    float* P   = (float*)alloc((size_t)8 * 8192 * 272 * 4);   // 71.3 MB partials

    k_pack<<<2048, 256, 0, stream>>>(sup, bits);
    k_cvt_x<<<4096, 256, 0, stream>>>(x, xb);
    k_cvt_w<<<512, 256, 0, stream>>>(W, Wbt);
    k_gemm_h<<<dim3(64, 4), 256, 0, stream>>>(xb, Wbt, h, B1t);
    k_st<<<2048, 256, 0, stream>>>(h, a, s, t);
    k_weights<<<32, 256, 0, stream>>>(s, t, wb, eL, eR, B1t);
    k_b2<<<dim3(32, 272), 256, 0, stream>>>(B1t, wb, B2t);
    k_mgemm<<<2048, 128, 0, stream>>>(bits, B1t, B2t, P);
    k_out<<<8192, 256, 0, stream>>>(P, eL, eR, outp);
}

// Round 11
// 183.269 us; speedup vs baseline: 1.4934x; 1.4934x over previous
//
#include <hip/hip_runtime.h>

// GraphAttentionLayer: x(8192,512) f32, support(8192,8192) i32{0,1},
// W(512,256) f32, a(512,1) f32  ->  out(8192,256) f32
//
// Decomposition (softmax shift cancels in numerator/denominator):
//   h = x@W (bf16 MFMA); s = h@a1, t = h@a2
//   top rows i<4096 : out = elu((eL*TL + eR*TR)/(eL*TL[256] + eR*TR[256]))
//   bot rows i>=4096: out = elu(TB/TB[256]),  TB = sup[4096:, :] @ (wb .* [h|1])
//
// v11 = round-6 (session-best) k_mgemm frozen + aux consolidation:
//   - x f32->bf16 conversion fused into k_gemm_h staging (k_cvt_x deleted)
//   - B2t generation fused into k_weights (k_b2 deleted)
//   - T5 s_setprio around the MFMA cluster
// k_mgemm: BM=128, BN=272, BK=32, K-split q=0..7 XCD-pinned. B -> 4 LDS bufs
// staged 3 ahead via global_load_lds; A(support) -> 3-slot register pipeline;
// counted s_waitcnt vmcnt(14) + raw s_barrier. Partials P[8], no atomics.

typedef short bf16x8 __attribute__((ext_vector_type(8)));
typedef float f32x4 __attribute__((ext_vector_type(4)));

static __device__ __forceinline__ unsigned short f2bf(float f) {
    unsigned int u = __builtin_bit_cast(unsigned int, f);
    unsigned int r = (u + 0x7FFFu + ((u >> 16) & 1u)) >> 16;
    return (unsigned short)r;
}
static __device__ __forceinline__ float bf2f(unsigned short s) {
    unsigned int u = ((unsigned int)s) << 16;
    return __builtin_bit_cast(float, u);
}
static __device__ __forceinline__ void glds16(const unsigned short* g, unsigned short* l) {
    __builtin_amdgcn_global_load_lds(
        (const __attribute__((address_space(1))) unsigned int*)(g),
        (__attribute__((address_space(3))) unsigned int*)(l), 16, 0, 0);
}
static __device__ __forceinline__ bf16x8 cvt8(float4 a, float4 b) {
    bf16x8 r;
    r[0] = (short)f2bf(a.x); r[1] = (short)f2bf(a.y);
    r[2] = (short)f2bf(a.z); r[3] = (short)f2bf(a.w);
    r[4] = (short)f2bf(b.x); r[5] = (short)f2bf(b.y);
    r[6] = (short)f2bf(b.z); r[7] = (short)f2bf(b.w);
    return r;
}

// ---- k1b: W [512][256] f32 -> Wbt [256][512] bf16 (n-major, k-contiguous)
__global__ __launch_bounds__(256) void k_cvt_w(const float* __restrict__ W,
                                               unsigned short* __restrict__ Wbt) {
    int idx = blockIdx.x * 256 + threadIdx.x;
    int n = idx >> 9, k = idx & 511;
    Wbt[idx] = f2bf(W[k * 256 + n]);
}

// ---- k2: h = x @ W (x converted f32->bf16 during staging).
//      Writes h row-major bf16 AND B1t [272][8192] rows 0..255 (h^T).
__global__ __launch_bounds__(256) void k_gemm_h(const float* __restrict__ x,
                                                const unsigned short* __restrict__ Wbt,
                                                unsigned short* __restrict__ h,
                                                unsigned short* __restrict__ B1t) {
    __shared__ unsigned short Asm[128][72];
    __shared__ unsigned short Bsm[64][72];
    int tid = threadIdx.x;
    int wv = tid >> 6, ln = tid & 63;
    int m0 = blockIdx.x * 128, n0 = blockIdx.y * 64;

    f32x4 acc[2][4];
#pragma unroll
    for (int i = 0; i < 2; i++)
#pragma unroll
        for (int j = 0; j < 4; j++) acc[i][j] = (f32x4)0.0f;

    for (int k0 = 0; k0 < 512; k0 += 64) {
        {   // stage A 128x64 with fused f32->bf16 conversion
            int r = tid >> 1, c = (tid & 1) * 32;
            const float* src = x + (long)(m0 + r) * 512 + k0 + c;
#pragma unroll
            for (int i = 0; i < 4; i++) {
                float4 a = *(const float4*)(src + i * 8);
                float4 b = *(const float4*)(src + i * 8 + 4);
                *(bf16x8*)&Asm[r][c + i * 8] = cvt8(a, b);
            }
        }
        {
            int r = tid >> 2, c = (tid & 3) * 16;
            const unsigned short* src = Wbt + (n0 + r) * 512 + k0 + c;
            *(bf16x8*)&Bsm[r][c]     = *(const bf16x8*)(src);
            *(bf16x8*)&Bsm[r][c + 8] = *(const bf16x8*)(src + 8);
        }
        __syncthreads();
        int lr = ln & 15, lk = (ln >> 4) * 8;
#pragma unroll
        for (int ks = 0; ks < 2; ks++) {
            int kk = ks * 32 + lk;
            bf16x8 a0 = *(const bf16x8*)&Asm[wv * 32 + lr][kk];
            bf16x8 a1 = *(const bf16x8*)&Asm[wv * 32 + 16 + lr][kk];
#pragma unroll
            for (int nt = 0; nt < 4; nt++) {
                bf16x8 b = *(const bf16x8*)&Bsm[nt * 16 + lr][kk];
                acc[0][nt] = __builtin_amdgcn_mfma_f32_16x16x32_bf16(a0, b, acc[0][nt], 0, 0, 0);
                acc[1][nt] = __builtin_amdgcn_mfma_f32_16x16x32_bf16(a1, b, acc[1][nt], 0, 0, 0);
            }
        }
        __syncthreads();
    }
    int lr = ln & 15, lrow = (ln >> 4) * 4;
#pragma unroll
    for (int mt = 0; mt < 2; mt++) {
#pragma unroll
        for (int nt = 0; nt < 4; nt++) {
            int mg = m0 + wv * 32 + mt * 16 + lrow;
            int ng = n0 + nt * 16 + lr;
            ushort4 tb = make_ushort4(f2bf(acc[mt][nt][0]), f2bf(acc[mt][nt][1]),
                                      f2bf(acc[mt][nt][2]), f2bf(acc[mt][nt][3]));
            h[(mg + 0) * 256 + ng] = tb.x;
            h[(mg + 1) * 256 + ng] = tb.y;
            h[(mg + 2) * 256 + ng] = tb.z;
            h[(mg + 3) * 256 + ng] = tb.w;
            *(ushort4*)&B1t[ng * 8192 + mg] = tb;
        }
    }
}

// ---- k3: s[j], t[j]
__global__ __launch_bounds__(256) void k_st(const unsigned short* __restrict__ h,
                                            const float* __restrict__ a,
                                            float* __restrict__ s, float* __restrict__ t) {
    int wv = threadIdx.x >> 6, ln = threadIdx.x & 63;
    int j = blockIdx.x * 4 + wv;
    ushort4 hv = *(const ushort4*)(h + j * 256 + ln * 4);
    float4 a1 = *(const float4*)(a + ln * 4);
    float4 a2 = *(const float4*)(a + 256 + ln * 4);
    float s_ = bf2f(hv.x) * a1.x + bf2f(hv.y) * a1.y + bf2f(hv.z) * a1.z + bf2f(hv.w) * a1.w;
    float t_ = bf2f(hv.x) * a2.x + bf2f(hv.y) * a2.y + bf2f(hv.z) * a2.z + bf2f(hv.w) * a2.w;
#pragma unroll
    for (int off = 32; off; off >>= 1) {
        s_ += __shfl_down(s_, off);
        t_ += __shfl_down(t_, off);
    }
    if (ln == 0) { s[j] = s_; t[j] = t_; }
}

// ---- k3b: wb / eL / eR; B1t aux rows; B2t = wb .* [B1t|1|0] (k_b2 fused)
__global__ __launch_bounds__(256) void k_weights(const float* __restrict__ s,
                                                 const float* __restrict__ t,
                                                 float* __restrict__ eL,
                                                 float* __restrict__ eR,
                                                 unsigned short* __restrict__ B1t,
                                                 unsigned short* __restrict__ B2t) {
    int j = blockIdx.x * 256 + threadIdx.x;
    float eb = s[(2 * j) & 8191] + t[(2 * j + 1) & 8191];
    eb = eb > 0.0f ? eb : 0.2f * eb;
    float wbj = expf(eb);
    if (j < 4096) {
        float cL = s[2 * j] + t[2 * j];
        cL = cL > 0.0f ? cL : 0.2f * cL;
        float cR = s[2 * j + 1] + t[2 * j + 1];
        cR = cR > 0.0f ? cR : 0.2f * cR;
        eL[j] = expf(cL);
        eR[j] = expf(cR);
    }
    B1t[256 * 8192 + j] = 0x3F80;
#pragma unroll
    for (int f = 257; f < 272; f++) B1t[f * 8192 + j] = 0;
    // B2t columns (coalesced across threads for each f)
#pragma unroll 4
    for (int f = 0; f < 256; f++)
        B2t[(long)f * 8192 + j] = f2bf(wbj * bf2f(B1t[(long)f * 8192 + j]));
    B2t[256l * 8192 + j] = f2bf(wbj);
#pragma unroll
    for (int f = 257; f < 272; f++) B2t[(long)f * 8192 + j] = 0;
}

// ---- k5: masked GEMM (round-6 structure, frozen; + T5 setprio).
static __device__ __forceinline__ bf16x8 cvt01(int4 a, int4 b) {
    bf16x8 r;
    r[0] = a.x ? (short)0x3F80 : (short)0; r[1] = a.y ? (short)0x3F80 : (short)0;
    r[2] = a.z ? (short)0x3F80 : (short)0; r[3] = a.w ? (short)0x3F80 : (short)0;
    r[4] = b.x ? (short)0x3F80 : (short)0; r[5] = b.y ? (short)0x3F80 : (short)0;
    r[6] = b.z ? (short)0x3F80 : (short)0; r[7] = b.w ? (short)0x3F80 : (short)0;
    return r;
}

__global__ __launch_bounds__(256, 2) void k_mgemm(const int* __restrict__ sup,
                                                  const unsigned short* __restrict__ B1t,
                                                  const unsigned short* __restrict__ B2t,
                                                  float* __restrict__ P) {
    __shared__ unsigned short Bsm[4 * 8704];   // 4 bufs x 17408 B, linear glds dest
    int tid = threadIdx.x, wv = tid >> 6, ln = tid & 63;
    int bid = blockIdx.x;
    int q = bid & 7;                 // XCD-pinned K-window
    int strip = bid >> 3;            // 0..63
    long K0 = (long)q * 1024;
    long m0 = (long)strip * 128;
    const unsigned short* Bt = (strip < 32) ? B1t : B2t;

    const unsigned short* sp[5];
    int cb[5];
#pragma unroll
    for (int i = 0; i < 4; i++) {
        int ch = i * 256 + wv * 64 + ln;
        int row = ch >> 2, c = ch & 3;
        cb[i] = (i * 256 + wv * 64) * 8;
        sp[i] = Bt + (long)row * 8192 + K0 + ((c ^ (row & 3)) << 3);
    }
    {
        int ch = 1024 + wv * 16 + (ln & 15);
        int row = ch >> 2, c = ch & 3;
        cb[4] = (1024 + wv * 16) * 8;
        sp[4] = Bt + (long)row * 8192 + K0 + ((c ^ (row & 3)) << 3);
    }

    const int* ap0 = sup + (m0 + wv * 32 + (ln & 15)) * 8192 + K0 + (ln >> 4) * 8;
    const int* ap1 = ap0 + 16 * 8192;

    f32x4 acc[2][17];
#pragma unroll
    for (int i = 0; i < 2; i++)
#pragma unroll
        for (int j = 0; j < 17; j++) acc[i][j] = (f32x4)0.0f;

#define STAGE_B(T) do {                                              \
        unsigned short* dst_ = Bsm + ((T) & 3) * 8704;               \
        long ko_ = (long)(T) * 32;                                   \
        glds16(sp[0] + ko_, dst_ + cb[0]);                           \
        glds16(sp[1] + ko_, dst_ + cb[1]);                           \
        glds16(sp[2] + ko_, dst_ + cb[2]);                           \
        glds16(sp[3] + ko_, dst_ + cb[3]);                           \
        if (ln < 16) glds16(sp[4] + ko_, dst_ + cb[4]);              \
    } while (0)

    int4 c0, c1, c2, c3;      // A(it)
    int4 n0, n1, n2, n3;      // A(it+1)
    int4 g0, g1, g2, g3;      // A(it+2) in flight

    // prologue: order = B0, A0, B1, A1, B2 (matches steady-state queue)
    STAGE_B(0);
    c0 = *(const int4*)(ap0); c1 = *(const int4*)(ap0 + 4);
    c2 = *(const int4*)(ap1); c3 = *(const int4*)(ap1 + 4);
    STAGE_B(1);
    n0 = *(const int4*)(ap0 + 32); n1 = *(const int4*)(ap0 + 36);
    n2 = *(const int4*)(ap1 + 32); n3 = *(const int4*)(ap1 + 36);
    STAGE_B(2);
    asm volatile("s_waitcnt vmcnt(14)" ::: "memory");
    __builtin_amdgcn_s_barrier();

    int lr = ln & 15;
    int swz16 = 16 * ((ln >> 4) ^ (ln & 3));

#pragma unroll 1
    for (int it = 0; it < 32; ++it) {
        if (it < 30) {   // issue A(it+2)
            const int* a0 = ap0 + (it + 2) * 32;
            const int* a1 = ap1 + (it + 2) * 32;
            g0 = *(const int4*)(a0); g1 = *(const int4*)(a0 + 4);
            g2 = *(const int4*)(a1); g3 = *(const int4*)(a1 + 4);
        }
        if (it < 29) STAGE_B(it + 3);   // issue B(it+3) (3 iters of slack)

        bf16x8 av0 = cvt01(c0, c1);
        bf16x8 av1 = cvt01(c2, c3);
        const char* base = (const char*)Bsm + (it & 3) * 17408 + 64 * lr + swz16;
        __builtin_amdgcn_s_setprio(1);
#pragma unroll
        for (int f = 0; f < 17; f++) {
            bf16x8 bv = *(const bf16x8*)(base + f * 1024);
            acc[0][f] = __builtin_amdgcn_mfma_f32_16x16x32_bf16(av0, bv, acc[0][f], 0, 0, 0);
            acc[1][f] = __builtin_amdgcn_mfma_f32_16x16x32_bf16(av1, bv, acc[1][f], 0, 0, 0);
        }
        __builtin_amdgcn_s_setprio(0);
        c0 = n0; c1 = n1; c2 = n2; c3 = n3;
        n0 = g0; n1 = g1; n2 = g2; n3 = g3;

        if (it < 29) {
            asm volatile("s_waitcnt vmcnt(14)" ::: "memory");
            __builtin_amdgcn_s_barrier();
        } else if (it == 29) {
            asm volatile("s_waitcnt vmcnt(9)" ::: "memory");
            __builtin_amdgcn_s_barrier();
        } else if (it == 30) {
            asm volatile("s_waitcnt vmcnt(0)" ::: "memory");
            __builtin_amdgcn_s_barrier();
        }
    }
#undef STAGE_B

    long grow = m0 + wv * 32 + (ln >> 4) * 4;
    float* op = P + ((long)q * 8192 + grow) * 272 + lr;
#pragma unroll
    for (int mf = 0; mf < 2; mf++)
#pragma unroll
        for (int f = 0; f < 17; f++)
#pragma unroll
            for (int r = 0; r < 4; r++)
                op[(long)(mf * 16 + r) * 272 + f * 16] = acc[mf][f][r];
}

// ---- k6: combine 8 partials + elu
__global__ __launch_bounds__(256) void k_out(const float* __restrict__ P,
                                             const float* __restrict__ eL,
                                             const float* __restrict__ eR,
                                             float* __restrict__ outp) {
    int i = blockIdx.x, f = threadIdx.x;
    const float* p = P + (long)i * 272;
    const long QS = 8192l * 272;
    float num, den;
    if (i < 4096) {
        float tln = 0, trn = 0, tld = 0, trd = 0;
#pragma unroll
        for (int q = 0; q < 4; q++) { tln += p[q * QS + f]; tld += p[q * QS + 256]; }
#pragma unroll
        for (int q = 4; q < 8; q++) { trn += p[q * QS + f]; trd += p[q * QS + 256]; }
        float el = eL[i], er = eR[i];
        num = el * tln + er * trn;
        den = el * tld + er * trd;
    } else {
        num = 0; den = 0;
#pragma unroll
        for (int q = 0; q < 8; q++) { num += p[q * QS + f]; den += p[q * QS + 256]; }
    }
    float r = num / den;
    outp[(long)i * 256 + f] = r > 0.0f ? r : expm1f(r);
}

extern "C" void kernel_launch(void* const* d_in, const int* in_sizes, int n_in,
                              void* d_out, int out_size, void* d_ws, size_t ws_size,
                              hipStream_t stream) {
    (void)in_sizes; (void)n_in; (void)out_size; (void)ws_size;
    const float* x = (const float*)d_in[0];
    const int* sup = (const int*)d_in[1];
    const float* W = (const float*)d_in[2];
    const float* a = (const float*)d_in[3];
    float* outp = (float*)d_out;

    char* ws = (char*)d_ws;
    size_t off = 0;
    auto alloc = [&](size_t bytes) -> void* {
        void* p = ws + off;
        off += (bytes + 255) & ~(size_t)255;
        return p;
    };
    unsigned short* Wbt = (unsigned short*)alloc(256 * 512 * 2);
    unsigned short* h   = (unsigned short*)alloc(8192 * 256 * 2);
    unsigned short* B1t = (unsigned short*)alloc(272 * 8192 * 2);
    unsigned short* B2t = (unsigned short*)alloc(272 * 8192 * 2);
    float* s   = (float*)alloc(8192 * 4);
    float* t   = (float*)alloc(8192 * 4);
    float* eL  = (float*)alloc(4096 * 4);
    float* eR  = (float*)alloc(4096 * 4);
    float* P   = (float*)alloc((size_t)8 * 8192 * 272 * 4);   // 71.3 MB partials

    k_cvt_w<<<512, 256, 0, stream>>>(W, Wbt);
    k_gemm_h<<<dim3(64, 4), 256, 0, stream>>>(x, Wbt, h, B1t);
    k_st<<<2048, 256, 0, stream>>>(h, a, s, t);
    k_weights<<<32, 256, 0, stream>>>(s, t, eL, eR, B1t, B2t);
    k_mgemm<<<512, 256, 0, stream>>>(sup, B1t, B2t, P);
    k_out<<<8192, 256, 0, stream>>>(P, eL, eR, outp);
}

// Round 12
// 174.372 us; speedup vs baseline: 1.5696x; 1.0510x over previous
//
#include <hip/hip_runtime.h>

// GraphAttentionLayer: x(8192,512) f32, support(8192,8192) i32{0,1},
// W(512,256) f32, a(512,1) f32  ->  out(8192,256) f32
//
// Decomposition (softmax shift cancels in numerator/denominator):
//   h = x@W (bf16 MFMA); s = h@a1, t = h@a2
//   top rows i<4096 : out = elu((eL*TL + eR*TR)/(eL*TL[256] + eR*TR[256]))
//   bot rows i>=4096: out = elu(TB/TB[256]),  TB = sup[4096:, :] @ (wb .* [h|1])
//
// v12 = round-6 (session best, 171 us) with ONE change: x f32->bf16 fused
// into k_gemm_h staging (k_cvt_x deleted). r11's other fusions reverted
// (k_weights B2t loop ran on 32 blocks = 1/8 CUs; setprio hurts lockstep
// GEMM per m190). k_mgemm byte-identical to round 6: BM=128/BN=272/BK=32,
// q=0..7 XCD-pinned K-split, 4 LDS B-bufs staged 3 ahead via global_load_lds,
// A 3-slot register pipeline, counted vmcnt(14) + raw s_barrier, partials
// P[8] plain stores.

typedef short bf16x8 __attribute__((ext_vector_type(8)));
typedef float f32x4 __attribute__((ext_vector_type(4)));

static __device__ __forceinline__ unsigned short f2bf(float f) {
    unsigned int u = __builtin_bit_cast(unsigned int, f);
    unsigned int r = (u + 0x7FFFu + ((u >> 16) & 1u)) >> 16;
    return (unsigned short)r;
}
static __device__ __forceinline__ float bf2f(unsigned short s) {
    unsigned int u = ((unsigned int)s) << 16;
    return __builtin_bit_cast(float, u);
}
static __device__ __forceinline__ void glds16(const unsigned short* g, unsigned short* l) {
    __builtin_amdgcn_global_load_lds(
        (const __attribute__((address_space(1))) unsigned int*)(g),
        (__attribute__((address_space(3))) unsigned int*)(l), 16, 0, 0);
}
static __device__ __forceinline__ bf16x8 cvt8(float4 a, float4 b) {
    bf16x8 r;
    r[0] = (short)f2bf(a.x); r[1] = (short)f2bf(a.y);
    r[2] = (short)f2bf(a.z); r[3] = (short)f2bf(a.w);
    r[4] = (short)f2bf(b.x); r[5] = (short)f2bf(b.y);
    r[6] = (short)f2bf(b.z); r[7] = (short)f2bf(b.w);
    return r;
}

// ---- k1b: W [512][256] f32 -> Wbt [256][512] bf16 (n-major, k-contiguous)
__global__ __launch_bounds__(256) void k_cvt_w(const float* __restrict__ W,
                                               unsigned short* __restrict__ Wbt) {
    int idx = blockIdx.x * 256 + threadIdx.x;
    int n = idx >> 9, k = idx & 511;
    Wbt[idx] = f2bf(W[k * 256 + n]);
}

// ---- k2: h = x @ W (x converted f32->bf16 during staging).
//      Writes h row-major bf16 AND B1t [272][8192] rows 0..255 (h^T).
__global__ __launch_bounds__(256) void k_gemm_h(const float* __restrict__ x,
                                                const unsigned short* __restrict__ Wbt,
                                                unsigned short* __restrict__ h,
                                                unsigned short* __restrict__ B1t) {
    __shared__ unsigned short Asm[128][72];
    __shared__ unsigned short Bsm[64][72];
    int tid = threadIdx.x;
    int wv = tid >> 6, ln = tid & 63;
    int m0 = blockIdx.x * 128, n0 = blockIdx.y * 64;

    f32x4 acc[2][4];
#pragma unroll
    for (int i = 0; i < 2; i++)
#pragma unroll
        for (int j = 0; j < 4; j++) acc[i][j] = (f32x4)0.0f;

    for (int k0 = 0; k0 < 512; k0 += 64) {
        {   // stage A 128x64 with fused f32->bf16 conversion
            int r = tid >> 1, c = (tid & 1) * 32;
            const float* src = x + (long)(m0 + r) * 512 + k0 + c;
#pragma unroll
            for (int i = 0; i < 4; i++) {
                float4 a = *(const float4*)(src + i * 8);
                float4 b = *(const float4*)(src + i * 8 + 4);
                *(bf16x8*)&Asm[r][c + i * 8] = cvt8(a, b);
            }
        }
        {
            int r = tid >> 2, c = (tid & 3) * 16;
            const unsigned short* src = Wbt + (n0 + r) * 512 + k0 + c;
            *(bf16x8*)&Bsm[r][c]     = *(const bf16x8*)(src);
            *(bf16x8*)&Bsm[r][c + 8] = *(const bf16x8*)(src + 8);
        }
        __syncthreads();
        int lr = ln & 15, lk = (ln >> 4) * 8;
#pragma unroll
        for (int ks = 0; ks < 2; ks++) {
            int kk = ks * 32 + lk;
            bf16x8 a0 = *(const bf16x8*)&Asm[wv * 32 + lr][kk];
            bf16x8 a1 = *(const bf16x8*)&Asm[wv * 32 + 16 + lr][kk];
#pragma unroll
            for (int nt = 0; nt < 4; nt++) {
                bf16x8 b = *(const bf16x8*)&Bsm[nt * 16 + lr][kk];
                acc[0][nt] = __builtin_amdgcn_mfma_f32_16x16x32_bf16(a0, b, acc[0][nt], 0, 0, 0);
                acc[1][nt] = __builtin_amdgcn_mfma_f32_16x16x32_bf16(a1, b, acc[1][nt], 0, 0, 0);
            }
        }
        __syncthreads();
    }
    int lr = ln & 15, lrow = (ln >> 4) * 4;
#pragma unroll
    for (int mt = 0; mt < 2; mt++) {
#pragma unroll
        for (int nt = 0; nt < 4; nt++) {
            int mg = m0 + wv * 32 + mt * 16 + lrow;
            int ng = n0 + nt * 16 + lr;
            ushort4 tb = make_ushort4(f2bf(acc[mt][nt][0]), f2bf(acc[mt][nt][1]),
                                      f2bf(acc[mt][nt][2]), f2bf(acc[mt][nt][3]));
            h[(mg + 0) * 256 + ng] = tb.x;
            h[(mg + 1) * 256 + ng] = tb.y;
            h[(mg + 2) * 256 + ng] = tb.z;
            h[(mg + 3) * 256 + ng] = tb.w;
            *(ushort4*)&B1t[ng * 8192 + mg] = tb;
        }
    }
}

// ---- k3: s[j], t[j]
__global__ __launch_bounds__(256) void k_st(const unsigned short* __restrict__ h,
                                            const float* __restrict__ a,
                                            float* __restrict__ s, float* __restrict__ t) {
    int wv = threadIdx.x >> 6, ln = threadIdx.x & 63;
    int j = blockIdx.x * 4 + wv;
    ushort4 hv = *(const ushort4*)(h + j * 256 + ln * 4);
    float4 a1 = *(const float4*)(a + ln * 4);
    float4 a2 = *(const float4*)(a + 256 + ln * 4);
    float s_ = bf2f(hv.x) * a1.x + bf2f(hv.y) * a1.y + bf2f(hv.z) * a1.z + bf2f(hv.w) * a1.w;
    float t_ = bf2f(hv.x) * a2.x + bf2f(hv.y) * a2.y + bf2f(hv.z) * a2.z + bf2f(hv.w) * a2.w;
#pragma unroll
    for (int off = 32; off; off >>= 1) {
        s_ += __shfl_down(s_, off);
        t_ += __shfl_down(t_, off);
    }
    if (ln == 0) { s[j] = s_; t[j] = t_; }
}

// ---- k3b: wb / eL / eR; fill B1t aux rows (256 = ones, 257..271 = 0)
__global__ __launch_bounds__(256) void k_weights(const float* __restrict__ s,
                                                 const float* __restrict__ t,
                                                 float* __restrict__ wb,
                                                 float* __restrict__ eL,
                                                 float* __restrict__ eR,
                                                 unsigned short* __restrict__ B1t) {
    int j = blockIdx.x * 256 + threadIdx.x;
    float eb = s[(2 * j) & 8191] + t[(2 * j + 1) & 8191];
    eb = eb > 0.0f ? eb : 0.2f * eb;
    wb[j] = expf(eb);
    if (j < 4096) {
        float cL = s[2 * j] + t[2 * j];
        cL = cL > 0.0f ? cL : 0.2f * cL;
        float cR = s[2 * j + 1] + t[2 * j + 1];
        cR = cR > 0.0f ? cR : 0.2f * cR;
        eL[j] = expf(cL);
        eR[j] = expf(cR);
    }
    B1t[256 * 8192 + j] = 0x3F80;
#pragma unroll
    for (int f = 257; f < 272; f++) B1t[f * 8192 + j] = 0;
}

// ---- k4: B2t[f][j] = wb[j] * B1t[f][j]  (fully parallel, reverted from r11)
__global__ __launch_bounds__(256) void k_b2(const unsigned short* __restrict__ B1t,
                                            const float* __restrict__ wb,
                                            unsigned short* __restrict__ B2t) {
    int j = blockIdx.x * 256 + threadIdx.x;
    int f = blockIdx.y;
    B2t[f * 8192 + j] = f2bf(wb[j] * bf2f(B1t[f * 8192 + j]));
}

// ---- k5: masked GEMM (round-6 structure, byte-identical).
static __device__ __forceinline__ bf16x8 cvt01(int4 a, int4 b) {
    bf16x8 r;
    r[0] = a.x ? (short)0x3F80 : (short)0; r[1] = a.y ? (short)0x3F80 : (short)0;
    r[2] = a.z ? (short)0x3F80 : (short)0; r[3] = a.w ? (short)0x3F80 : (short)0;
    r[4] = b.x ? (short)0x3F80 : (short)0; r[5] = b.y ? (short)0x3F80 : (short)0;
    r[6] = b.z ? (short)0x3F80 : (short)0; r[7] = b.w ? (short)0x3F80 : (short)0;
    return r;
}

__global__ __launch_bounds__(256, 2) void k_mgemm(const int* __restrict__ sup,
                                                  const unsigned short* __restrict__ B1t,
                                                  const unsigned short* __restrict__ B2t,
                                                  float* __restrict__ P) {
    __shared__ unsigned short Bsm[4 * 8704];   // 4 bufs x 17408 B, linear glds dest
    int tid = threadIdx.x, wv = tid >> 6, ln = tid & 63;
    int bid = blockIdx.x;
    int q = bid & 7;                 // XCD-pinned K-window
    int strip = bid >> 3;            // 0..63
    long K0 = (long)q * 1024;
    long m0 = (long)strip * 128;
    const unsigned short* Bt = (strip < 32) ? B1t : B2t;

    const unsigned short* sp[5];
    int cb[5];
#pragma unroll
    for (int i = 0; i < 4; i++) {
        int ch = i * 256 + wv * 64 + ln;
        int row = ch >> 2, c = ch & 3;
        cb[i] = (i * 256 + wv * 64) * 8;
        sp[i] = Bt + (long)row * 8192 + K0 + ((c ^ (row & 3)) << 3);
    }
    {
        int ch = 1024 + wv * 16 + (ln & 15);
        int row = ch >> 2, c = ch & 3;
        cb[4] = (1024 + wv * 16) * 8;
        sp[4] = Bt + (long)row * 8192 + K0 + ((c ^ (row & 3)) << 3);
    }

    const int* ap0 = sup + (m0 + wv * 32 + (ln & 15)) * 8192 + K0 + (ln >> 4) * 8;
    const int* ap1 = ap0 + 16 * 8192;

    f32x4 acc[2][17];
#pragma unroll
    for (int i = 0; i < 2; i++)
#pragma unroll
        for (int j = 0; j < 17; j++) acc[i][j] = (f32x4)0.0f;

#define STAGE_B(T) do {                                              \
        unsigned short* dst_ = Bsm + ((T) & 3) * 8704;               \
        long ko_ = (long)(T) * 32;                                   \
        glds16(sp[0] + ko_, dst_ + cb[0]);                           \
        glds16(sp[1] + ko_, dst_ + cb[1]);                           \
        glds16(sp[2] + ko_, dst_ + cb[2]);                           \
        glds16(sp[3] + ko_, dst_ + cb[3]);                           \
        if (ln < 16) glds16(sp[4] + ko_, dst_ + cb[4]);              \
    } while (0)

    int4 c0, c1, c2, c3;      // A(it)
    int4 n0, n1, n2, n3;      // A(it+1)
    int4 g0, g1, g2, g3;      // A(it+2) in flight

    // prologue: order = B0, A0, B1, A1, B2 (matches steady-state queue)
    STAGE_B(0);
    c0 = *(const int4*)(ap0); c1 = *(const int4*)(ap0 + 4);
    c2 = *(const int4*)(ap1); c3 = *(const int4*)(ap1 + 4);
    STAGE_B(1);
    n0 = *(const int4*)(ap0 + 32); n1 = *(const int4*)(ap0 + 36);
    n2 = *(const int4*)(ap1 + 32); n3 = *(const int4*)(ap1 + 36);
    STAGE_B(2);
    asm volatile("s_waitcnt vmcnt(14)" ::: "memory");
    __builtin_amdgcn_s_barrier();

    int lr = ln & 15;
    int swz16 = 16 * ((ln >> 4) ^ (ln & 3));

#pragma unroll 1
    for (int it = 0; it < 32; ++it) {
        if (it < 30) {   // issue A(it+2)
            const int* a0 = ap0 + (it + 2) * 32;
            const int* a1 = ap1 + (it + 2) * 32;
            g0 = *(const int4*)(a0); g1 = *(const int4*)(a0 + 4);
            g2 = *(const int4*)(a1); g3 = *(const int4*)(a1 + 4);
        }
        if (it < 29) STAGE_B(it + 3);   // issue B(it+3) (3 iters of slack)

        bf16x8 av0 = cvt01(c0, c1);
        bf16x8 av1 = cvt01(c2, c3);
        const char* base = (const char*)Bsm + (it & 3) * 17408 + 64 * lr + swz16;
#pragma unroll
        for (int f = 0; f < 17; f++) {
            bf16x8 bv = *(const bf16x8*)(base + f * 1024);
            acc[0][f] = __builtin_amdgcn_mfma_f32_16x16x32_bf16(av0, bv, acc[0][f], 0, 0, 0);
            acc[1][f] = __builtin_amdgcn_mfma_f32_16x16x32_bf16(av1, bv, acc[1][f], 0, 0, 0);
        }
        c0 = n0; c1 = n1; c2 = n2; c3 = n3;
        n0 = g0; n1 = g1; n2 = g2; n3 = g3;

        if (it < 29) {
            asm volatile("s_waitcnt vmcnt(14)" ::: "memory");
            __builtin_amdgcn_s_barrier();
        } else if (it == 29) {
            asm volatile("s_waitcnt vmcnt(9)" ::: "memory");
            __builtin_amdgcn_s_barrier();
        } else if (it == 30) {
            asm volatile("s_waitcnt vmcnt(0)" ::: "memory");
            __builtin_amdgcn_s_barrier();
        }
    }
#undef STAGE_B

    long grow = m0 + wv * 32 + (ln >> 4) * 4;
    float* op = P + ((long)q * 8192 + grow) * 272 + lr;
#pragma unroll
    for (int mf = 0; mf < 2; mf++)
#pragma unroll
        for (int f = 0; f < 17; f++)
#pragma unroll
            for (int r = 0; r < 4; r++)
                op[(long)(mf * 16 + r) * 272 + f * 16] = acc[mf][f][r];
}

// ---- k6: combine 8 partials + elu
__global__ __launch_bounds__(256) void k_out(const float* __restrict__ P,
                                             const float* __restrict__ eL,
                                             const float* __restrict__ eR,
                                             float* __restrict__ outp) {
    int i = blockIdx.x, f = threadIdx.x;
    const float* p = P + (long)i * 272;
    const long QS = 8192l * 272;
    float num, den;
    if (i < 4096) {
        float tln = 0, trn = 0, tld = 0, trd = 0;
#pragma unroll
        for (int q = 0; q < 4; q++) { tln += p[q * QS + f]; tld += p[q * QS + 256]; }
#pragma unroll
        for (int q = 4; q < 8; q++) { trn += p[q * QS + f]; trd += p[q * QS + 256]; }
        float el = eL[i], er = eR[i];
        num = el * tln + er * trn;
        den = el * tld + er * trd;
    } else {
        num = 0; den = 0;
#pragma unroll
        for (int q = 0; q < 8; q++) { num += p[q * QS + f]; den += p[q * QS + 256]; }
    }
    float r = num / den;
    outp[(long)i * 256 + f] = r > 0.0f ? r : expm1f(r);
}

extern "C" void kernel_launch(void* const* d_in, const int* in_sizes, int n_in,
                              void* d_out, int out_size, void* d_ws, size_t ws_size,
                              hipStream_t stream) {
    (void)in_sizes; (void)n_in; (void)out_size; (void)ws_size;
    const float* x = (const float*)d_in[0];
    const int* sup = (const int*)d_in[1];
    const float* W = (const float*)d_in[2];
    const float* a = (const float*)d_in[3];
    float* outp = (float*)d_out;

    char* ws = (char*)d_ws;
    size_t off = 0;
    auto alloc = [&](size_t bytes) -> void* {
        void* p = ws + off;
        off += (bytes + 255) & ~(size_t)255;
        return p;
    };
    unsigned short* Wbt = (unsigned short*)alloc(256 * 512 * 2);
    unsigned short* h   = (unsigned short*)alloc(8192 * 256 * 2);
    unsigned short* B1t = (unsigned short*)alloc(272 * 8192 * 2);
    unsigned short* B2t = (unsigned short*)alloc(272 * 8192 * 2);
    float* s   = (float*)alloc(8192 * 4);
    float* t   = (float*)alloc(8192 * 4);
    float* wb  = (float*)alloc(8192 * 4);
    float* eL  = (float*)alloc(4096 * 4);
    float* eR  = (float*)alloc(4096 * 4);
    float* P   = (float*)alloc((size_t)8 * 8192 * 272 * 4);   // 71.3 MB partials

    k_cvt_w<<<512, 256, 0, stream>>>(W, Wbt);
    k_gemm_h<<<dim3(64, 4), 256, 0, stream>>>(x, Wbt, h, B1t);
    k_st<<<2048, 256, 0, stream>>>(h, a, s, t);
    k_weights<<<32, 256, 0, stream>>>(s, t, wb, eL, eR, B1t);
    k_b2<<<dim3(32, 272), 256, 0, stream>>>(B1t, wb, B2t);
    k_mgemm<<<512, 256, 0, stream>>>(sup, B1t, B2t, P);
    k_out<<<8192, 256, 0, stream>>>(P, eL, eR, outp);
}